// Round 2
// baseline (459.037 us; speedup 1.0000x reference)
//
#include <hip/hip_runtime.h>

#define BT 128
#define D  256
#define H  512

// Output element offsets (flat fp32, reference return order)
#define OFF_HT  0          // (BT, 2H)  = 131072
#define OFF_C1  131072     // (BT, H)   = 65536
#define OFF_C2  196608
#define OFF_N1  262144
#define OFF_N2  327680
#define OFF_T1  393216
#define OFF_T2  458752
#define OFF_W11 524288     // (BT, D, H) = 16777216
#define OFF_W12 17301504
#define OFF_W21 34078720
#define OFF_W22 50855936

#define SMALL_BLOCKS 256           // (BT*H)/256
// Big path: BT*D = 32768 "bd" rows, each row = 128 float4 (H/4).
// Each block: 256 threads = 2 bd-rows in flight, ITER=8 rows each -> 16 rows/block.
#define BIG_ITER     8
#define BD_PER_BLOCK 16            // 2 * BIG_ITER
#define BIG_BLOCKS   2048          // 32768 / 16

// Native vector type so __builtin_nontemporal_{load,store} accepts it
// (HIP's float4 is a class and is rejected by the builtin).
typedef float f32x4 __attribute__((ext_vector_type(4)));

// Fused kernel.
//  blocks [0, 256):        per-(b,h) work — xw dot products, c/n/t traces, h_t
//  blocks [256, 256+2048): W-trace streaming; A/B/g recomputed once per block
//                          into LDS, hoisted to registers, then 8 iterations
//                          of 64B-in/64B-out nontemporal streaming per thread.
__global__ __launch_bounds__(256) void rtu_fused(
    const float*  __restrict__ x_t,
    const float*  __restrict__ h1,   const float* __restrict__ h2,
    const float*  __restrict__ mnu1, const float* __restrict__ mnu2,
    const float*  __restrict__ mth1, const float* __restrict__ mth2,
    const f32x4*  __restrict__ mw11, const f32x4* __restrict__ mw12,
    const f32x4*  __restrict__ mw21, const f32x4* __restrict__ mw22,
    const float*  __restrict__ w1,   const float* __restrict__ w2,
    const float*  __restrict__ nu_log, const float* __restrict__ theta_log,
    float* __restrict__ out)
{
    __shared__ float sA[H];
    __shared__ float sB[H];
    __shared__ float sG[H];
    __shared__ float xs[D];

    const int tid = threadIdx.x;

    if (blockIdx.x < SMALL_BLOCKS) {
        // ---------------- small path: one thread per (b,h) ----------------
        const int idx = blockIdx.x * 256 + tid;     // idx == b*H + h
        const int b   = idx >> 9;                   // uniform per block
        const int h   = idx & (H - 1);

        xs[tid] = x_t[b * D + tid];
        __syncthreads();

        const float exp_nu = expf(nu_log[h]);
        const float r      = expf(-exp_nu);
        const float theta  = expf(theta_log[h]);
        const float g      = sqrtf(fmaxf(1.0f - r * r, 0.0f));
        float s, c;
        sincosf(theta, &s, &c);
        const float A = r * c;
        const float B = r * s;
        const float dA_dnu = -A * exp_nu;
        const float dB_dnu = -B * exp_nu;
        const float dg_dnu = (r * r) * exp_nu / g;
        const float dA_dth = -B * theta;
        const float dB_dth =  A * theta;

        float xw1 = 0.0f, xw2 = 0.0f;
        #pragma unroll 8
        for (int d = 0; d < D; ++d) {
            const float xv = xs[d];
            xw1 = fmaf(xv, w1[d * H + h], xw1);
            xw2 = fmaf(xv, w2[d * H + h], xw2);
        }

        const float h1v = h1[idx],  h2v = h2[idx];
        const float mn1 = mnu1[idx], mn2 = mnu2[idx];
        const float mt1 = mth1[idx], mt2 = mth2[idx];

        const float c1v = A * h1v - B * h2v + g * xw1;
        const float c2v = B * h1v + A * h2v + g * xw2;

        const float n1v = A * mn1 - B * mn2 + dA_dnu * h1v - dB_dnu * h2v + dg_dnu * xw1;
        const float n2v = B * mn1 + A * mn2 + dB_dnu * h1v + dA_dnu * h2v + dg_dnu * xw2;

        const float t1v = A * mt1 - B * mt2 + dA_dth * h1v - dB_dth * h2v;
        const float t2v = B * mt1 + A * mt2 + dB_dth * h1v + dA_dth * h2v;

        out[OFF_HT + b * (2 * H) + h]     = fmaxf(c1v, 0.0f);
        out[OFF_HT + b * (2 * H) + H + h] = fmaxf(c2v, 0.0f);
        out[OFF_C1 + idx] = c1v;
        out[OFF_C2 + idx] = c2v;
        out[OFF_N1 + idx] = n1v;
        out[OFF_N2 + idx] = n2v;
        out[OFF_T1 + idx] = t1v;
        out[OFF_T2 + idx] = t2v;
        return;
    }

    // ---------------- big path: W-trace streaming ----------------
    // Fill A/B/g for all 512 h into LDS (2 per thread), then hoist this
    // thread's 4 h-lanes into registers.
    #pragma unroll
    for (int i = 0; i < 2; ++i) {
        const int h = tid + i * 256;
        const float exp_nu = expf(nu_log[h]);
        const float r      = expf(-exp_nu);
        const float theta  = expf(theta_log[h]);
        float s, c;
        sincosf(theta, &s, &c);
        sA[h] = r * c;
        sB[h] = r * s;
        sG[h] = sqrtf(fmaxf(1.0f - r * r, 0.0f));
    }
    __syncthreads();

    const int hq = tid & 127;                  // float4 index within h (h/4)
    const int lr = tid >> 7;                   // 0 or 1: local bd row

    const f32x4 A4 = ((const f32x4*)sA)[hq];
    const f32x4 B4 = ((const f32x4*)sB)[hq];
    const f32x4 g4 = ((const f32x4*)sG)[hq];

    int bd = (blockIdx.x - SMALL_BLOCKS) * BD_PER_BLOCK + lr;  // b*D + d

    f32x4* __restrict__ o11p = (f32x4*)(out + OFF_W11);
    f32x4* __restrict__ o12p = (f32x4*)(out + OFF_W12);
    f32x4* __restrict__ o21p = (f32x4*)(out + OFF_W21);
    f32x4* __restrict__ o22p = (f32x4*)(out + OFF_W22);

    #pragma unroll
    for (int it = 0; it < BIG_ITER; ++it, bd += 2) {
        const int e = bd * 128 + hq;           // float4 element index

        const float x = x_t[bd];               // uniform per wave (broadcast)

        const f32x4 m11 = __builtin_nontemporal_load(mw11 + e);
        const f32x4 m12 = __builtin_nontemporal_load(mw12 + e);
        const f32x4 m21 = __builtin_nontemporal_load(mw21 + e);
        const f32x4 m22 = __builtin_nontemporal_load(mw22 + e);

        const f32x4 gx = g4 * x;

        f32x4 o11, o12, o21, o22;
        #pragma unroll
        for (int j = 0; j < 4; ++j) {
            o11[j] = fmaf(A4[j], m11[j], fmaf(-B4[j], m12[j], gx[j]));
            o12[j] = fmaf(B4[j], m11[j], A4[j] * m12[j]);
            o21[j] = fmaf(A4[j], m21[j], -B4[j] * m22[j]);
            o22[j] = fmaf(B4[j], m21[j], fmaf(A4[j], m22[j], gx[j]));
        }

        __builtin_nontemporal_store(o11, o11p + e);
        __builtin_nontemporal_store(o12, o12p + e);
        __builtin_nontemporal_store(o21, o21p + e);
        __builtin_nontemporal_store(o22, o22p + e);
    }
}

extern "C" void kernel_launch(void* const* d_in, const int* in_sizes, int n_in,
                              void* d_out, int out_size, void* d_ws, size_t ws_size,
                              hipStream_t stream) {
    const float* x_t   = (const float*)d_in[0];
    const float* h1    = (const float*)d_in[1];
    const float* h2    = (const float*)d_in[2];
    const float* mnu1  = (const float*)d_in[3];
    const float* mnu2  = (const float*)d_in[4];
    const float* mth1  = (const float*)d_in[5];
    const float* mth2  = (const float*)d_in[6];
    const float* mw11  = (const float*)d_in[7];
    const float* mw12  = (const float*)d_in[8];
    const float* mw21  = (const float*)d_in[9];
    const float* mw22  = (const float*)d_in[10];
    const float* w1    = (const float*)d_in[11];
    const float* w2    = (const float*)d_in[12];
    const float* nu_log    = (const float*)d_in[13];
    const float* theta_log = (const float*)d_in[14];

    float* out = (float*)d_out;

    rtu_fused<<<SMALL_BLOCKS + BIG_BLOCKS, 256, 0, stream>>>(
        x_t, h1, h2, mnu1, mnu2, mth1, mth2,
        (const f32x4*)mw11, (const f32x4*)mw12,
        (const f32x4*)mw21, (const f32x4*)mw22,
        w1, w2, nu_log, theta_log, out);
}

// Round 3
// 458.100 us; speedup vs baseline: 1.0020x; 1.0020x over previous
//
#include <hip/hip_runtime.h>

#define BT 128
#define D  256
#define H  512

// Output element offsets (flat fp32, reference return order)
#define OFF_HT  0          // (BT, 2H)  = 131072
#define OFF_C1  131072     // (BT, H)   = 65536
#define OFF_C2  196608
#define OFF_N1  262144
#define OFF_N2  327680
#define OFF_T1  393216
#define OFF_T2  458752
#define OFF_W11 524288     // (BT, D, H) = 16777216
#define OFF_W12 17301504
#define OFF_W21 34078720
#define OFF_W22 50855936

#define SMALL_BLOCKS 256           // (BT*H)/256
// Big path: BT*D = 32768 "bd" rows. Each block processes BIG_ITER rows;
// per row: 256 threads = 2 pairs x 128 float4 (H/4). One pair of arrays
// per half-block -> 2 loads + 2 stores per thread per iteration.
#define BIG_ITER     16
#define BIG_BLOCKS   2048          // 32768 / BIG_ITER

// Native vector type so __builtin_nontemporal_{load,store} accepts it
// (HIP's float4 is a class and is rejected by the builtin).
typedef float f32x4 __attribute__((ext_vector_type(4)));

// Fused kernel.
//  blocks [0, 256):        per-(b,h) work — xw dot products, c/n/t traces, h_t
//  blocks [256, 256+2048): W-trace streaming. Threads 0-127 own the
//                          (mw11,mw12)->(W11,W12) pair, threads 128-255 the
//                          (mw21,mw22)->(W21,W22) pair. Explicit register
//                          double-buffer: iter i+1 loads issue BEFORE iter i
//                          stores so the vmcnt wait never chains on stores.
__global__ __launch_bounds__(256) void rtu_fused(
    const float*  __restrict__ x_t,
    const float*  __restrict__ h1,   const float* __restrict__ h2,
    const float*  __restrict__ mnu1, const float* __restrict__ mnu2,
    const float*  __restrict__ mth1, const float* __restrict__ mth2,
    const f32x4*  __restrict__ mw11, const f32x4* __restrict__ mw12,
    const f32x4*  __restrict__ mw21, const f32x4* __restrict__ mw22,
    const float*  __restrict__ w1,   const float* __restrict__ w2,
    const float*  __restrict__ nu_log, const float* __restrict__ theta_log,
    float* __restrict__ out)
{
    __shared__ float sA[H];
    __shared__ float sB[H];
    __shared__ float sG[H];
    __shared__ float xs[D];

    const int tid = threadIdx.x;

    if (blockIdx.x < SMALL_BLOCKS) {
        // ---------------- small path: one thread per (b,h) ----------------
        const int idx = blockIdx.x * 256 + tid;     // idx == b*H + h
        const int b   = idx >> 9;                   // uniform per block
        const int h   = idx & (H - 1);

        xs[tid] = x_t[b * D + tid];
        __syncthreads();

        const float exp_nu = expf(nu_log[h]);
        const float r      = expf(-exp_nu);
        const float theta  = expf(theta_log[h]);
        const float g      = sqrtf(fmaxf(1.0f - r * r, 0.0f));
        float s, c;
        sincosf(theta, &s, &c);
        const float A = r * c;
        const float B = r * s;
        const float dA_dnu = -A * exp_nu;
        const float dB_dnu = -B * exp_nu;
        const float dg_dnu = (r * r) * exp_nu / g;
        const float dA_dth = -B * theta;
        const float dB_dth =  A * theta;

        float xw1 = 0.0f, xw2 = 0.0f;
        #pragma unroll 8
        for (int d = 0; d < D; ++d) {
            const float xv = xs[d];
            xw1 = fmaf(xv, w1[d * H + h], xw1);
            xw2 = fmaf(xv, w2[d * H + h], xw2);
        }

        const float h1v = h1[idx],  h2v = h2[idx];
        const float mn1 = mnu1[idx], mn2 = mnu2[idx];
        const float mt1 = mth1[idx], mt2 = mth2[idx];

        const float c1v = A * h1v - B * h2v + g * xw1;
        const float c2v = B * h1v + A * h2v + g * xw2;

        const float n1v = A * mn1 - B * mn2 + dA_dnu * h1v - dB_dnu * h2v + dg_dnu * xw1;
        const float n2v = B * mn1 + A * mn2 + dB_dnu * h1v + dA_dnu * h2v + dg_dnu * xw2;

        const float t1v = A * mt1 - B * mt2 + dA_dth * h1v - dB_dth * h2v;
        const float t2v = B * mt1 + A * mt2 + dB_dth * h1v + dA_dth * h2v;

        out[OFF_HT + b * (2 * H) + h]     = fmaxf(c1v, 0.0f);
        out[OFF_HT + b * (2 * H) + H + h] = fmaxf(c2v, 0.0f);
        out[OFF_C1 + idx] = c1v;
        out[OFF_C2 + idx] = c2v;
        out[OFF_N1 + idx] = n1v;
        out[OFF_N2 + idx] = n2v;
        out[OFF_T1 + idx] = t1v;
        out[OFF_T2 + idx] = t2v;
        return;
    }

    // ---------------- big path: W-trace streaming ----------------
    // Fill A/B/g for all 512 h into LDS (2 per thread), then hoist this
    // thread's 4 h-lanes into registers.
    #pragma unroll
    for (int i = 0; i < 2; ++i) {
        const int h = tid + i * 256;
        const float exp_nu = expf(nu_log[h]);
        const float r      = expf(-exp_nu);
        const float theta  = expf(theta_log[h]);
        float s, c;
        sincosf(theta, &s, &c);
        sA[h] = r * c;
        sB[h] = r * s;
        sG[h] = sqrtf(fmaxf(1.0f - r * r, 0.0f));
    }
    __syncthreads();

    const int hq   = tid & 127;                // float4 index within h (h/4)
    const int pair = tid >> 7;                 // 0: (11,12)  1: (21,22)

    const f32x4 A4 = ((const f32x4*)sA)[hq];
    const f32x4 B4 = ((const f32x4*)sB)[hq];
    const f32x4 g4 = ((const f32x4*)sG)[hq];

    // gx lands in the FIRST output for pair 0 (W11) and in the SECOND
    // output for pair 1 (W22); zero-out the other via per-thread selector.
    const f32x4 gF = pair ? (f32x4)(0.0f) : g4;
    const f32x4 gS = pair ? g4 : (f32x4)(0.0f);

    const int bd0 = (blockIdx.x - SMALL_BLOCKS) * BIG_ITER;   // first row

    const f32x4* __restrict__ s0 = (pair ? mw21 : mw11) + bd0 * 128 + hq;
    const f32x4* __restrict__ s1 = (pair ? mw22 : mw12) + bd0 * 128 + hq;
    f32x4* __restrict__ d0 = (f32x4*)(out + (pair ? OFF_W21 : OFF_W11)) + bd0 * 128 + hq;
    f32x4* __restrict__ d1 = (f32x4*)(out + (pair ? OFF_W22 : OFF_W12)) + bd0 * 128 + hq;

    // register double-buffer pipeline
    f32x4 a = __builtin_nontemporal_load(s0);
    f32x4 b = __builtin_nontemporal_load(s1);
    float x = x_t[bd0];

    #pragma unroll
    for (int it = 0; it < BIG_ITER; ++it) {
        f32x4 an = a, bn = b;
        float xn = x;
        if (it + 1 < BIG_ITER) {
            an = __builtin_nontemporal_load(s0 + (it + 1) * 128);
            bn = __builtin_nontemporal_load(s1 + (it + 1) * 128);
            xn = x_t[bd0 + it + 1];
        }

        const f32x4 gxf = gF * x;
        const f32x4 gxs = gS * x;

        f32x4 of, os;
        #pragma unroll
        for (int j = 0; j < 4; ++j) {
            of[j] = fmaf(A4[j], a[j], fmaf(-B4[j], b[j], gxf[j]));
            os[j] = fmaf(B4[j], a[j], fmaf(A4[j], b[j], gxs[j]));
        }

        __builtin_nontemporal_store(of, d0 + it * 128);
        __builtin_nontemporal_store(os, d1 + it * 128);

        a = an; b = bn; x = xn;
    }
}

extern "C" void kernel_launch(void* const* d_in, const int* in_sizes, int n_in,
                              void* d_out, int out_size, void* d_ws, size_t ws_size,
                              hipStream_t stream) {
    const float* x_t   = (const float*)d_in[0];
    const float* h1    = (const float*)d_in[1];
    const float* h2    = (const float*)d_in[2];
    const float* mnu1  = (const float*)d_in[3];
    const float* mnu2  = (const float*)d_in[4];
    const float* mth1  = (const float*)d_in[5];
    const float* mth2  = (const float*)d_in[6];
    const float* mw11  = (const float*)d_in[7];
    const float* mw12  = (const float*)d_in[8];
    const float* mw21  = (const float*)d_in[9];
    const float* mw22  = (const float*)d_in[10];
    const float* w1    = (const float*)d_in[11];
    const float* w2    = (const float*)d_in[12];
    const float* nu_log    = (const float*)d_in[13];
    const float* theta_log = (const float*)d_in[14];

    float* out = (float*)d_out;

    rtu_fused<<<SMALL_BLOCKS + BIG_BLOCKS, 256, 0, stream>>>(
        x_t, h1, h2, mnu1, mnu2, mth1, mth2,
        (const f32x4*)mw11, (const f32x4*)mw12,
        (const f32x4*)mw21, (const f32x4*)mw22,
        w1, w2, nu_log, theta_log, out);
}